// Round 1
// 517.371 us; speedup vs baseline: 1.0617x; 1.0617x over previous
//
#include <hip/hip_runtime.h>
#include <math.h>

#define NTH 256
#define LAM 0.01f
#define WS_WT_BYTES 589824   // 4 planes * 8 blocks * 96*96 * 2B (bf16 W^T)

typedef __attribute__((ext_vector_type(8))) short short8;
typedef __attribute__((ext_vector_type(8))) unsigned short ushort8;
typedef __attribute__((ext_vector_type(4))) float f32x4;

__device__ __forceinline__ ushort f2bf(float f) {
    union { float f; unsigned u; } c; c.f = f;
    unsigned u = c.u;
    u += 0x7fffu + ((u >> 16) & 1u);   // round-to-nearest-even
    return (ushort)(u >> 16);
}

// ---------------------------------------------------------------------------
// Stockham radix-2 complex FFT of length 2048 in LDS. 11 stages, autosorting.
// ---------------------------------------------------------------------------
__device__ __forceinline__ float2* fft2048_stockham(float2* bufA, float2* bufB,
                                                    int tid, float sign) {
    float2* src = bufA;
    float2* dst = bufB;
    for (int Ns = 1; Ns < 2048; Ns <<= 1) {
        float w0 = sign * (float)M_PI / (float)Ns;
        for (int j = tid; j < 1024; j += NTH) {
            float2 a = src[j];
            float2 b = src[j + 1024];
            int r = j & (Ns - 1);
            float ang = w0 * (float)r;
            float s, c;
            __sincosf(ang, &s, &c);
            float bwx = b.x * c - b.y * s;
            float bwy = b.x * s + b.y * c;
            int d = ((j - r) << 1) + r;
            dst[d]      = make_float2(a.x + bwx, a.y + bwy);
            dst[d + Ns] = make_float2(a.x - bwx, a.y - bwy);
        }
        __syncthreads();
        float2* t = src; src = dst; dst = t;
    }
    return src;
}

// ---------------------------------------------------------------------------
// Forward rfft per row (ortho), packed output (4096 floats / row).
// ---------------------------------------------------------------------------
__global__ __launch_bounds__(NTH) void k_rfft_fwd(const float* __restrict__ x,
                                                  float* __restrict__ out) {
    __shared__ float2 bufA[2048];
    __shared__ float2 bufB[2048];
    const int row = blockIdx.x;
    const float* xr = x + (size_t)row * 4096;
    float* orow = out + (size_t)row * 4096;
    const int tid = threadIdx.x;

    for (int t = tid; t < 2048; t += NTH)
        bufA[t] = *(const float2*)(xr + 2 * t);
    __syncthreads();

    float2* Z = fft2048_stockham(bufA, bufB, tid, -1.0f);

    const float scale = 1.0f / 64.0f;
    for (int k = tid; k <= 2048; k += NTH) {
        float2 zk = Z[k & 2047];
        float2 zn = Z[(2048 - k) & 2047];
        float Ar = 0.5f * (zk.x + zn.x), Ai = 0.5f * (zk.y - zn.y);
        float Br = 0.5f * (zk.x - zn.x), Bi = 0.5f * (zk.y + zn.y);
        float ang = -(float)M_PI * (float)k / 2048.0f;
        float s, c;
        __sincosf(ang, &s, &c);
        float wBr = c * Br - s * Bi;
        float wBi = c * Bi + s * Br;
        float Xr = (Ar + wBi) * scale;
        float Xi = (Ai - wBr) * scale;
        if (k == 0)          orow[0] = Xr;
        else if (k == 2048)  orow[1] = Xr;
        else                 *(float2*)(orow + 2 * k) = make_float2(Xr, Xi);
    }
}

// ---------------------------------------------------------------------------
// Weight preprocessing: fp32 W[a][n][i][o] -> bf16 W^T in ws: [a][n][o][i].
// a: 0=w1re 1=w1im 2=w2re 3=w2im. Runs once per launch, ~µs.
// ---------------------------------------------------------------------------
__global__ __launch_bounds__(NTH) void k_prep(
    const float* __restrict__ w1_re, const float* __restrict__ w1_im,
    const float* __restrict__ w2_re, const float* __restrict__ w2_im,
    ushort* __restrict__ wt) {
    int gid = blockIdx.x * NTH + threadIdx.x;   // 0 .. 294911
    if (gid >= 294912) return;
    int a   = gid / 73728;
    int rem = gid - a * 73728;
    int n   = rem / 9216;
    int r2  = rem - n * 9216;
    int o   = r2 / 96;
    int i   = r2 - o * 96;
    const float* src = (a == 0) ? w1_re : (a == 1) ? w1_im : (a == 2) ? w2_re : w2_im;
    wt[gid] = f2bf(src[(n * 96 + i) * 96 + o]);
}

// ---------------------------------------------------------------------------
// MFMA mixer v3: barrier-free.
//  - xb only in LDS (26.6 KB -> up to 6 blocks/CU); wb eliminated.
//  - Each wave's LDS footprint is its own 16-mode stripe (rows mw..mw+15):
//    stage, A-frag reads, h-writes, layer-2 reads are all wave-private, so
//    NO __syncthreads anywhere (same-wave ds ordering via lgkmcnt).
//  - W^T fragments loaded directly from global bf16 wt (L2-resident, 576 KB
//    total shared by all blocks with same n).
// Grid (33 m-tiles, 8 blocks, 16 batch) x 256 thr (4 waves).
// ---------------------------------------------------------------------------
__global__ __launch_bounds__(NTH, 4) void k_mix3(
    float* __restrict__ io, const ushort* __restrict__ wt,
    const float* __restrict__ b1_re, const float* __restrict__ b1_im,
    const float* __restrict__ b2_re, const float* __restrict__ b2_im) {
    __shared__ __align__(16) ushort xb[2][64][104];   // 26624 B

    const int mt = blockIdx.x;
    const int n  = blockIdx.y;
    const int b  = blockIdx.z;
    const int tid  = threadIdx.x;
    const int lane = tid & 63;
    const int wv   = tid >> 6;
    const int m0 = mt * 64;
    const int mw = wv * 16;
    float* base = io + ((size_t)b * 768 + (size_t)n * 96) * 4096;

    // ---- per-wave stage of own 16-mode stripe (no barrier needed)
    {
        const int mm = lane & 15;          // mode within stripe
        const int m  = m0 + mw + mm;
        const int i0 = lane >> 4;          // starting channel 0..3
        for (int i = i0; i < 96; i += 4) {
            const float* row = base + (size_t)i * 4096;
            float re = 0.f, im = 0.f;
            if (m == 0)          { re = row[0]; }
            else if (m == 2048)  { re = row[1]; }
            else if (m < 2048)   { float2 v = *(const float2*)(row + 2 * m); re = v.x; im = v.y; }
            xb[0][mw + mm][i] = f2bf(re);
            xb[1][mw + mm][i] = f2bf(im);
        }
    }

    const int lc = lane & 15;
    const int kl = 8 * (lane >> 4);
    const int mrow = mw + lc;
    const ushort* wn  = wt + (size_t)n * 9216;        // w1_re^T; +73728 per plane
    const ushort* wn2 = wn + 2 * 73728;               // w2_re^T

    float b1r[6], b1i[6];
#pragma unroll
    for (int nt = 0; nt < 6; ++nt) {
        b1r[nt] = b1_re[n * 96 + nt * 16 + lc];
        b1i[nt] = b1_im[n * 96 + nt * 16 + lc];
    }

    f32x4 accR[6], accI[6];
    const f32x4 zero = {0.f, 0.f, 0.f, 0.f};
#pragma unroll
    for (int nt = 0; nt < 6; ++nt) { accR[nt] = zero; accI[nt] = zero; }

    // ---- layer 1 (weight frags straight from global; all L2 hits)
#pragma unroll
    for (int kk = 0; kk < 3; ++kk) {
        const int k0 = kk * 32 + kl;
        short8 ar = *(const short8*)&xb[0][mrow][k0];
        short8 ai = *(const short8*)&xb[1][mrow][k0];
        short8 nai;
#pragma unroll
        for (int j = 0; j < 8; ++j) nai[j] = ai[j] ^ (short)0x8000;
#pragma unroll
        for (int nt = 0; nt < 6; ++nt) {
            const ushort* wp = wn + (nt * 16 + lc) * 96 + k0;
            short8 br = *(const short8*)(wp);            // w1_re^T
            short8 bi = *(const short8*)(wp + 73728);    // w1_im^T
            accR[nt] = __builtin_amdgcn_mfma_f32_16x16x32_bf16(ar,  br, accR[nt], 0, 0, 0);
            accR[nt] = __builtin_amdgcn_mfma_f32_16x16x32_bf16(nai, bi, accR[nt], 0, 0, 0);
            accI[nt] = __builtin_amdgcn_mfma_f32_16x16x32_bf16(ar,  bi, accI[nt], 0, 0, 0);
            accI[nt] = __builtin_amdgcn_mfma_f32_16x16x32_bf16(ai,  br, accI[nt], 0, 0, 0);
        }
    }
    // crelu -> h into own stripe (same-wave LDS dependency only)
#pragma unroll
    for (int nt = 0; nt < 6; ++nt) {
#pragma unroll
        for (int q = 0; q < 4; ++q) {
            int m = mw + 4 * (lane >> 4) + q;
            xb[0][m][nt * 16 + lc] = f2bf(fmaxf(accR[nt][q] + b1r[nt], 0.f));
            xb[1][m][nt * 16 + lc] = f2bf(fmaxf(accI[nt][q] + b1i[nt], 0.f));
        }
    }

    // ---- layer 2
#pragma unroll
    for (int nt = 0; nt < 6; ++nt) { accR[nt] = zero; accI[nt] = zero; }
#pragma unroll
    for (int kk = 0; kk < 3; ++kk) {
        const int k0 = kk * 32 + kl;
        short8 ar = *(const short8*)&xb[0][mrow][k0];
        short8 ai = *(const short8*)&xb[1][mrow][k0];
        short8 nai;
#pragma unroll
        for (int j = 0; j < 8; ++j) nai[j] = ai[j] ^ (short)0x8000;
#pragma unroll
        for (int nt = 0; nt < 6; ++nt) {
            const ushort* wp = wn2 + (nt * 16 + lc) * 96 + k0;
            short8 br = *(const short8*)(wp);            // w2_re^T
            short8 bi = *(const short8*)(wp + 73728);    // w2_im^T
            accR[nt] = __builtin_amdgcn_mfma_f32_16x16x32_bf16(ar,  br, accR[nt], 0, 0, 0);
            accR[nt] = __builtin_amdgcn_mfma_f32_16x16x32_bf16(nai, bi, accR[nt], 0, 0, 0);
            accI[nt] = __builtin_amdgcn_mfma_f32_16x16x32_bf16(ar,  bi, accI[nt], 0, 0, 0);
            accI[nt] = __builtin_amdgcn_mfma_f32_16x16x32_bf16(ai,  br, accI[nt], 0, 0, 0);
        }
    }

    // softshrink + in-place packed store (b2 biases loaded late to cut live regs)
    float b2r[6], b2i[6];
#pragma unroll
    for (int nt = 0; nt < 6; ++nt) {
        b2r[nt] = b2_re[n * 96 + nt * 16 + lc];
        b2i[nt] = b2_im[n * 96 + nt * 16 + lc];
    }
#pragma unroll
    for (int nt = 0; nt < 6; ++nt) {
#pragma unroll
        for (int q = 0; q < 4; ++q) {
            int m = m0 + mw + 4 * (lane >> 4) + q;
            float vr = accR[nt][q] + b2r[nt];
            float vi = accI[nt][q] + b2i[nt];
            float sr = copysignf(fmaxf(fabsf(vr) - LAM, 0.f), vr);
            float si = copysignf(fmaxf(fabsf(vi) - LAM, 0.f), vi);
            float* row = base + (size_t)(nt * 16 + lc) * 4096;
            if (m == 0)          row[0] = sr;
            else if (m == 2048)  row[1] = sr;
            else if (m < 2048)   *(float2*)(row + 2 * m) = make_float2(sr, si);
        }
    }
}

// ---------------------------------------------------------------------------
// Fallback mixer (no ws dependency).
// ---------------------------------------------------------------------------
__global__ __launch_bounds__(NTH) void k_mix_fallback(
    float* __restrict__ io,
    const float* __restrict__ w1_re, const float* __restrict__ w1_im,
    const float* __restrict__ w2_re, const float* __restrict__ w2_im,
    const float* __restrict__ b1_re, const float* __restrict__ b1_im,
    const float* __restrict__ b2_re, const float* __restrict__ b2_im) {
    __shared__ __align__(16) ushort xb[2][64][96];
    __shared__ __align__(16) ushort wb[2][96][104];

    const int mt = blockIdx.x;
    const int n  = blockIdx.y;
    const int b  = blockIdx.z;
    const int tid = threadIdx.x;
    const int lane = tid & 63;
    const int wv   = tid >> 6;
    const int m0 = mt * 64;
    float* base = io + ((size_t)b * 768 + (size_t)n * 96) * 4096;

    for (int idx = tid; idx < 96 * 64; idx += NTH) {
        int i = idx >> 6, mm = idx & 63;
        int m = m0 + mm;
        const float* row = base + (size_t)i * 4096;
        float re = 0.f, im = 0.f;
        if (m == 0) { re = row[0]; }
        else if (m == 2048) { re = row[1]; }
        else if (m < 2048) { float2 v = *(const float2*)(row + 2 * m); re = v.x; im = v.y; }
        xb[0][mm][i] = f2bf(re);
        xb[1][mm][i] = f2bf(im);
    }
    const float* W1r = w1_re + (size_t)n * 9216;
    const float* W1i = w1_im + (size_t)n * 9216;
    for (int idx = tid; idx < 9216; idx += NTH) {
        int i = idx / 96, o = idx - i * 96;
        wb[0][o][i] = f2bf(W1r[idx]);
        wb[1][o][i] = f2bf(W1i[idx]);
    }
    const int lc = lane & 15;
    float b1r[6], b1i[6], b2r[6], b2i[6];
#pragma unroll
    for (int nt = 0; nt < 6; ++nt) {
        b1r[nt] = b1_re[n * 96 + nt * 16 + lc];
        b1i[nt] = b1_im[n * 96 + nt * 16 + lc];
        b2r[nt] = b2_re[n * 96 + nt * 16 + lc];
        b2i[nt] = b2_im[n * 96 + nt * 16 + lc];
    }
    __syncthreads();

    const int mw = wv * 16;
    const int kl = 8 * (lane >> 4);
    const int mrow = mw + lc;

    f32x4 accR[6], accI[6];
    const f32x4 zero = {0.f, 0.f, 0.f, 0.f};
#pragma unroll
    for (int nt = 0; nt < 6; ++nt) { accR[nt] = zero; accI[nt] = zero; }

#pragma unroll
    for (int kk = 0; kk < 3; ++kk) {
        int k0 = kk * 32 + kl;
        short8 ar = *(const short8*)&xb[0][mrow][k0];
        short8 ai = *(const short8*)&xb[1][mrow][k0];
        short8 nai;
#pragma unroll
        for (int j = 0; j < 8; ++j) nai[j] = ai[j] ^ (short)0x8000;
#pragma unroll
        for (int nt = 0; nt < 6; ++nt) {
            short8 br = *(const short8*)&wb[0][nt * 16 + lc][k0];
            short8 bi = *(const short8*)&wb[1][nt * 16 + lc][k0];
            accR[nt] = __builtin_amdgcn_mfma_f32_16x16x32_bf16(ar,  br, accR[nt], 0, 0, 0);
            accR[nt] = __builtin_amdgcn_mfma_f32_16x16x32_bf16(nai, bi, accR[nt], 0, 0, 0);
            accI[nt] = __builtin_amdgcn_mfma_f32_16x16x32_bf16(ar,  bi, accI[nt], 0, 0, 0);
            accI[nt] = __builtin_amdgcn_mfma_f32_16x16x32_bf16(ai,  br, accI[nt], 0, 0, 0);
        }
    }
#pragma unroll
    for (int nt = 0; nt < 6; ++nt) {
#pragma unroll
        for (int q = 0; q < 4; ++q) {
            int m = mw + 4 * (lane >> 4) + q;
            float hr = fmaxf(accR[nt][q] + b1r[nt], 0.f);
            float hi = fmaxf(accI[nt][q] + b1i[nt], 0.f);
            xb[0][m][nt * 16 + lc] = f2bf(hr);
            xb[1][m][nt * 16 + lc] = f2bf(hi);
        }
    }
    __syncthreads();

    const float* W2r = w2_re + (size_t)n * 9216;
    const float* W2i = w2_im + (size_t)n * 9216;
    for (int idx = tid; idx < 9216; idx += NTH) {
        int i = idx / 96, o = idx - i * 96;
        wb[0][o][i] = f2bf(W2r[idx]);
        wb[1][o][i] = f2bf(W2i[idx]);
    }
    __syncthreads();

#pragma unroll
    for (int nt = 0; nt < 6; ++nt) { accR[nt] = zero; accI[nt] = zero; }
#pragma unroll
    for (int kk = 0; kk < 3; ++kk) {
        int k0 = kk * 32 + kl;
        short8 ar = *(const short8*)&xb[0][mrow][k0];
        short8 ai = *(const short8*)&xb[1][mrow][k0];
        short8 nai;
#pragma unroll
        for (int j = 0; j < 8; ++j) nai[j] = ai[j] ^ (short)0x8000;
#pragma unroll
        for (int nt = 0; nt < 6; ++nt) {
            short8 br = *(const short8*)&wb[0][nt * 16 + lc][k0];
            short8 bi = *(const short8*)&wb[1][nt * 16 + lc][k0];
            accR[nt] = __builtin_amdgcn_mfma_f32_16x16x32_bf16(ar,  br, accR[nt], 0, 0, 0);
            accR[nt] = __builtin_amdgcn_mfma_f32_16x16x32_bf16(nai, bi, accR[nt], 0, 0, 0);
            accI[nt] = __builtin_amdgcn_mfma_f32_16x16x32_bf16(ar,  bi, accI[nt], 0, 0, 0);
            accI[nt] = __builtin_amdgcn_mfma_f32_16x16x32_bf16(ai,  br, accI[nt], 0, 0, 0);
        }
    }
#pragma unroll
    for (int nt = 0; nt < 6; ++nt) {
#pragma unroll
        for (int q = 0; q < 4; ++q) {
            int m = m0 + mw + 4 * (lane >> 4) + q;
            float vr = accR[nt][q] + b2r[nt];
            float vi = accI[nt][q] + b2i[nt];
            float sr = copysignf(fmaxf(fabsf(vr) - LAM, 0.f), vr);
            float si = copysignf(fmaxf(fabsf(vi) - LAM, 0.f), vi);
            float* row = base + (size_t)(nt * 16 + lc) * 4096;
            if (m == 0)          row[0] = sr;
            else if (m == 2048)  row[1] = sr;
            else if (m < 2048)   *(float2*)(row + 2 * m) = make_float2(sr, si);
        }
    }
}

// ---------------------------------------------------------------------------
// Inverse rfft per row (ortho) + residual add, in-place on packed spectrum.
// ---------------------------------------------------------------------------
__global__ __launch_bounds__(NTH) void k_irfft_add(const float* __restrict__ x,
                                                   float* __restrict__ io) {
    __shared__ float2 bufA[2048];
    __shared__ float2 bufB[2048];
    const int row = blockIdx.x;
    const float* xr = x + (size_t)row * 4096;
    float* orow = io + (size_t)row * 4096;
    const int tid = threadIdx.x;
    const float scale = 1.0f / 32.0f;

    for (int k = tid; k < 2048; k += NTH) {
        float Xr, Xi, Yr, Yi;
        if (k == 0) {
            Xr = orow[0]; Xi = 0.f; Yr = orow[1]; Yi = 0.f;
        } else {
            float2 a  = *(const float2*)(orow + 2 * k);
            float2 bq = *(const float2*)(orow + 2 * (2048 - k));
            Xr = a.x; Xi = a.y; Yr = bq.x; Yi = bq.y;
        }
        float Fer = 0.5f * (Xr + Yr), Fei = 0.5f * (Xi - Yi);
        float Dr  = 0.5f * (Xr - Yr), Di  = 0.5f * (Xi + Yi);
        float ang = (float)M_PI * (float)k / 2048.0f;
        float s, c;
        __sincosf(ang, &s, &c);
        float For = c * Dr - s * Di;
        float Foi = c * Di + s * Dr;
        bufA[k] = make_float2((Fer - Foi) * scale, (Fei + For) * scale);
    }
    __syncthreads();

    float2* Zt = fft2048_stockham(bufA, bufB, tid, 1.0f);

    for (int t = tid; t < 2048; t += NTH) {
        float2 z  = Zt[t];
        float2 xv = *(const float2*)(xr + 2 * t);
        *(float2*)(orow + 2 * t) = make_float2(z.x + xv.x, z.y + xv.y);
    }
}

// ---------------------------------------------------------------------------
extern "C" void kernel_launch(void* const* d_in, const int* in_sizes, int n_in,
                              void* d_out, int out_size, void* d_ws, size_t ws_size,
                              hipStream_t stream) {
    const float* x     = (const float*)d_in[0];
    const float* w1_re = (const float*)d_in[1];
    const float* w1_im = (const float*)d_in[2];
    const float* w2_re = (const float*)d_in[3];
    const float* w2_im = (const float*)d_in[4];
    const float* b1_re = (const float*)d_in[5];
    const float* b1_im = (const float*)d_in[6];
    const float* b2_re = (const float*)d_in[7];
    const float* b2_im = (const float*)d_in[8];
    float* out = (float*)d_out;

    k_rfft_fwd<<<12288, NTH, 0, stream>>>(x, out);
    if (ws_size >= (size_t)WS_WT_BYTES) {
        ushort* wt = (ushort*)d_ws;
        k_prep<<<(294912 + NTH - 1) / NTH, NTH, 0, stream>>>(w1_re, w1_im, w2_re, w2_im, wt);
        k_mix3<<<dim3(33, 8, 16), NTH, 0, stream>>>(out, wt, b1_re, b1_im, b2_re, b2_im);
    } else {
        k_mix_fallback<<<dim3(33, 8, 16), NTH, 0, stream>>>(out, w1_re, w1_im, w2_re, w2_im,
                                                            b1_re, b1_im, b2_re, b2_im);
    }
    k_irfft_add<<<12288, NTH, 0, stream>>>(x, out);
}

// Round 2
// 446.336 us; speedup vs baseline: 1.2306x; 1.1592x over previous
//
#include <hip/hip_runtime.h>
#include <math.h>

#define NTH 256
#define LAM 0.01f
#define WS_WT_BYTES 589824   // 4 planes * 8 blocks * 96*96 * 2B (bf16 W^T)

typedef __attribute__((ext_vector_type(8))) short short8;
typedef __attribute__((ext_vector_type(8))) unsigned short ushort8;
typedef __attribute__((ext_vector_type(4))) float f32x4;

__device__ __forceinline__ ushort f2bf(float f) {
    union { float f; unsigned u; } c; c.f = f;
    unsigned u = c.u;
    u += 0x7fffu + ((u >> 16) & 1u);   // round-to-nearest-even
    return (ushort)(u >> 16);
}

// LDS index padding: breaks power-of-2 stride bank conflicts (float2 elems,
// 32 banks -> pad one float2 every 32).
__device__ __forceinline__ int pad(int i) { return i + (i >> 5); }
#define FFT_LDS_SZ 2112   // pad(2047)=2110, round up

// ---------------------------------------------------------------------------
// Stockham complex FFT of length 2048 in LDS: 5 radix-4 stages + 1 radix-2.
// 6 barriers (was 11), 1 sincos per radix-4 butterfly (w^2, w^3 derived by
// complex mult). Padded indexing on both buffers.
// ---------------------------------------------------------------------------
__device__ __forceinline__ float2* fft2048_stockham(float2* bufA, float2* bufB,
                                                    int tid, float sign) {
    float2* src = bufA;
    float2* dst = bufB;
    // ---- 5 radix-4 stages: Ns = 1, 4, 16, 64, 256
#pragma unroll
    for (int s = 0; s < 5; ++s) {
        const int Ns = 1 << (2 * s);
        const float w0 = sign * (float)M_PI / (float)(2 * Ns);
#pragma unroll
        for (int u = tid; u < 512; u += NTH) {
            const int r = u & (Ns - 1);
            float2 x0 = src[pad(u)];
            float2 x1 = src[pad(u + 512)];
            float2 x2 = src[pad(u + 1024)];
            float2 x3 = src[pad(u + 1536)];
            float ang = w0 * (float)r;
            float s1, c1;
            __sincosf(ang, &s1, &c1);
            float c2 = c1 * c1 - s1 * s1, s2 = 2.f * c1 * s1;
            float c3 = c2 * c1 - s2 * s1, s3 = c2 * s1 + s2 * c1;
            float2 t1 = make_float2(x1.x * c1 - x1.y * s1, x1.x * s1 + x1.y * c1);
            float2 t2 = make_float2(x2.x * c2 - x2.y * s2, x2.x * s2 + x2.y * c2);
            float2 t3 = make_float2(x3.x * c3 - x3.y * s3, x3.x * s3 + x3.y * c3);
            float2 apc = make_float2(x0.x + t2.x, x0.y + t2.y);
            float2 amc = make_float2(x0.x - t2.x, x0.y - t2.y);
            float2 bpd = make_float2(t1.x + t3.x, t1.y + t3.y);
            float2 bmd = make_float2(t1.x - t3.x, t1.y - t3.y);
            // e = sign * i * bmd  (y1 = amc + e, y3 = amc - e for both signs)
            float2 e = make_float2(-sign * bmd.y, sign * bmd.x);
            const int d = ((u - r) << 2) + r;
            dst[pad(d)]          = make_float2(apc.x + bpd.x, apc.y + bpd.y);
            dst[pad(d + Ns)]     = make_float2(amc.x + e.x,   amc.y + e.y);
            dst[pad(d + 2 * Ns)] = make_float2(apc.x - bpd.x, apc.y - bpd.y);
            dst[pad(d + 3 * Ns)] = make_float2(amc.x - e.x,   amc.y - e.y);
        }
        __syncthreads();
        float2* t = src; src = dst; dst = t;
    }
    // ---- final radix-2 stage, Ns = 1024 (d == u, contiguous writes)
    const float w1 = sign * (float)M_PI / 1024.0f;
    for (int u = tid; u < 1024; u += NTH) {
        float2 a = src[pad(u)];
        float2 b = src[pad(u + 1024)];
        float ang = w1 * (float)u;
        float sn, cn;
        __sincosf(ang, &sn, &cn);
        float bwx = b.x * cn - b.y * sn;
        float bwy = b.x * sn + b.y * cn;
        dst[pad(u)]        = make_float2(a.x + bwx, a.y + bwy);
        dst[pad(u + 1024)] = make_float2(a.x - bwx, a.y - bwy);
    }
    __syncthreads();
    return dst;
}

// ---------------------------------------------------------------------------
// Forward rfft per row (ortho), packed output (4096 floats / row).
// ---------------------------------------------------------------------------
__global__ __launch_bounds__(NTH) void k_rfft_fwd(const float* __restrict__ x,
                                                  float* __restrict__ out) {
    __shared__ float2 bufA[FFT_LDS_SZ];
    __shared__ float2 bufB[FFT_LDS_SZ];
    const int row = blockIdx.x;
    const float* xr = x + (size_t)row * 4096;
    float* orow = out + (size_t)row * 4096;
    const int tid = threadIdx.x;

    for (int t = tid; t < 2048; t += NTH)
        bufA[pad(t)] = *(const float2*)(xr + 2 * t);
    __syncthreads();

    float2* Z = fft2048_stockham(bufA, bufB, tid, -1.0f);

    const float scale = 1.0f / 64.0f;
    for (int k = tid; k <= 2048; k += NTH) {
        float2 zk = Z[pad(k & 2047)];
        float2 zn = Z[pad((2048 - k) & 2047)];
        float Ar = 0.5f * (zk.x + zn.x), Ai = 0.5f * (zk.y - zn.y);
        float Br = 0.5f * (zk.x - zn.x), Bi = 0.5f * (zk.y + zn.y);
        float ang = -(float)M_PI * (float)k / 2048.0f;
        float s, c;
        __sincosf(ang, &s, &c);
        float wBr = c * Br - s * Bi;
        float wBi = c * Bi + s * Br;
        float Xr = (Ar + wBi) * scale;
        float Xi = (Ai - wBr) * scale;
        if (k == 0)          orow[0] = Xr;
        else if (k == 2048)  orow[1] = Xr;
        else                 *(float2*)(orow + 2 * k) = make_float2(Xr, Xi);
    }
}

// ---------------------------------------------------------------------------
// Weight preprocessing: fp32 W[a][n][i][o] -> bf16 W^T in ws: [a][n][o][i].
// a: 0=w1re 1=w1im 2=w2re 3=w2im. Runs once per launch, ~µs.
// ---------------------------------------------------------------------------
__global__ __launch_bounds__(NTH) void k_prep(
    const float* __restrict__ w1_re, const float* __restrict__ w1_im,
    const float* __restrict__ w2_re, const float* __restrict__ w2_im,
    ushort* __restrict__ wt) {
    int gid = blockIdx.x * NTH + threadIdx.x;   // 0 .. 294911
    if (gid >= 294912) return;
    int a   = gid / 73728;
    int rem = gid - a * 73728;
    int n   = rem / 9216;
    int r2  = rem - n * 9216;
    int o   = r2 / 96;
    int i   = r2 - o * 96;
    const float* src = (a == 0) ? w1_re : (a == 1) ? w1_im : (a == 2) ? w2_re : w2_im;
    wt[gid] = f2bf(src[(n * 96 + i) * 96 + o]);
}

// ---------------------------------------------------------------------------
// MFMA mixer v3: barrier-free.
//  - xb only in LDS (26.6 KB); wb eliminated.
//  - Each wave's LDS footprint is its own 16-mode stripe: no __syncthreads.
//  - W^T fragments loaded directly from global bf16 wt (L2-resident).
// Grid (33 m-tiles, 8 blocks, 16 batch) x 256 thr (4 waves).
// ---------------------------------------------------------------------------
__global__ __launch_bounds__(NTH, 4) void k_mix3(
    float* __restrict__ io, const ushort* __restrict__ wt,
    const float* __restrict__ b1_re, const float* __restrict__ b1_im,
    const float* __restrict__ b2_re, const float* __restrict__ b2_im) {
    __shared__ __align__(16) ushort xb[2][64][104];   // 26624 B

    const int mt = blockIdx.x;
    const int n  = blockIdx.y;
    const int b  = blockIdx.z;
    const int tid  = threadIdx.x;
    const int lane = tid & 63;
    const int wv   = tid >> 6;
    const int m0 = mt * 64;
    const int mw = wv * 16;
    float* base = io + ((size_t)b * 768 + (size_t)n * 96) * 4096;

    // ---- per-wave stage of own 16-mode stripe (no barrier needed)
    {
        const int mm = lane & 15;          // mode within stripe
        const int m  = m0 + mw + mm;
        const int i0 = lane >> 4;          // starting channel 0..3
        for (int i = i0; i < 96; i += 4) {
            const float* row = base + (size_t)i * 4096;
            float re = 0.f, im = 0.f;
            if (m == 0)          { re = row[0]; }
            else if (m == 2048)  { re = row[1]; }
            else if (m < 2048)   { float2 v = *(const float2*)(row + 2 * m); re = v.x; im = v.y; }
            xb[0][mw + mm][i] = f2bf(re);
            xb[1][mw + mm][i] = f2bf(im);
        }
    }

    const int lc = lane & 15;
    const int kl = 8 * (lane >> 4);
    const int mrow = mw + lc;
    const ushort* wn  = wt + (size_t)n * 9216;        // w1_re^T; +73728 per plane
    const ushort* wn2 = wn + 2 * 73728;               // w2_re^T

    float b1r[6], b1i[6];
#pragma unroll
    for (int nt = 0; nt < 6; ++nt) {
        b1r[nt] = b1_re[n * 96 + nt * 16 + lc];
        b1i[nt] = b1_im[n * 96 + nt * 16 + lc];
    }

    f32x4 accR[6], accI[6];
    const f32x4 zero = {0.f, 0.f, 0.f, 0.f};
#pragma unroll
    for (int nt = 0; nt < 6; ++nt) { accR[nt] = zero; accI[nt] = zero; }

    // ---- layer 1 (weight frags straight from global; all L2 hits)
#pragma unroll
    for (int kk = 0; kk < 3; ++kk) {
        const int k0 = kk * 32 + kl;
        short8 ar = *(const short8*)&xb[0][mrow][k0];
        short8 ai = *(const short8*)&xb[1][mrow][k0];
        short8 nai;
#pragma unroll
        for (int j = 0; j < 8; ++j) nai[j] = ai[j] ^ (short)0x8000;
#pragma unroll
        for (int nt = 0; nt < 6; ++nt) {
            const ushort* wp = wn + (nt * 16 + lc) * 96 + k0;
            short8 br = *(const short8*)(wp);            // w1_re^T
            short8 bi = *(const short8*)(wp + 73728);    // w1_im^T
            accR[nt] = __builtin_amdgcn_mfma_f32_16x16x32_bf16(ar,  br, accR[nt], 0, 0, 0);
            accR[nt] = __builtin_amdgcn_mfma_f32_16x16x32_bf16(nai, bi, accR[nt], 0, 0, 0);
            accI[nt] = __builtin_amdgcn_mfma_f32_16x16x32_bf16(ar,  bi, accI[nt], 0, 0, 0);
            accI[nt] = __builtin_amdgcn_mfma_f32_16x16x32_bf16(ai,  br, accI[nt], 0, 0, 0);
        }
    }
    // crelu -> h into own stripe (same-wave LDS dependency only)
#pragma unroll
    for (int nt = 0; nt < 6; ++nt) {
#pragma unroll
        for (int q = 0; q < 4; ++q) {
            int m = mw + 4 * (lane >> 4) + q;
            xb[0][m][nt * 16 + lc] = f2bf(fmaxf(accR[nt][q] + b1r[nt], 0.f));
            xb[1][m][nt * 16 + lc] = f2bf(fmaxf(accI[nt][q] + b1i[nt], 0.f));
        }
    }

    // ---- layer 2
#pragma unroll
    for (int nt = 0; nt < 6; ++nt) { accR[nt] = zero; accI[nt] = zero; }
#pragma unroll
    for (int kk = 0; kk < 3; ++kk) {
        const int k0 = kk * 32 + kl;
        short8 ar = *(const short8*)&xb[0][mrow][k0];
        short8 ai = *(const short8*)&xb[1][mrow][k0];
        short8 nai;
#pragma unroll
        for (int j = 0; j < 8; ++j) nai[j] = ai[j] ^ (short)0x8000;
#pragma unroll
        for (int nt = 0; nt < 6; ++nt) {
            const ushort* wp = wn2 + (nt * 16 + lc) * 96 + k0;
            short8 br = *(const short8*)(wp);            // w2_re^T
            short8 bi = *(const short8*)(wp + 73728);    // w2_im^T
            accR[nt] = __builtin_amdgcn_mfma_f32_16x16x32_bf16(ar,  br, accR[nt], 0, 0, 0);
            accR[nt] = __builtin_amdgcn_mfma_f32_16x16x32_bf16(nai, bi, accR[nt], 0, 0, 0);
            accI[nt] = __builtin_amdgcn_mfma_f32_16x16x32_bf16(ar,  bi, accI[nt], 0, 0, 0);
            accI[nt] = __builtin_amdgcn_mfma_f32_16x16x32_bf16(ai,  br, accI[nt], 0, 0, 0);
        }
    }

    // softshrink + in-place packed store (b2 biases loaded late to cut live regs)
    float b2r[6], b2i[6];
#pragma unroll
    for (int nt = 0; nt < 6; ++nt) {
        b2r[nt] = b2_re[n * 96 + nt * 16 + lc];
        b2i[nt] = b2_im[n * 96 + nt * 16 + lc];
    }
#pragma unroll
    for (int nt = 0; nt < 6; ++nt) {
#pragma unroll
        for (int q = 0; q < 4; ++q) {
            int m = m0 + mw + 4 * (lane >> 4) + q;
            float vr = accR[nt][q] + b2r[nt];
            float vi = accI[nt][q] + b2i[nt];
            float sr = copysignf(fmaxf(fabsf(vr) - LAM, 0.f), vr);
            float si = copysignf(fmaxf(fabsf(vi) - LAM, 0.f), vi);
            float* row = base + (size_t)(nt * 16 + lc) * 4096;
            if (m == 0)          row[0] = sr;
            else if (m == 2048)  row[1] = sr;
            else if (m < 2048)   *(float2*)(row + 2 * m) = make_float2(sr, si);
        }
    }
}

// ---------------------------------------------------------------------------
// Fallback mixer (no ws dependency).
// ---------------------------------------------------------------------------
__global__ __launch_bounds__(NTH) void k_mix_fallback(
    float* __restrict__ io,
    const float* __restrict__ w1_re, const float* __restrict__ w1_im,
    const float* __restrict__ w2_re, const float* __restrict__ w2_im,
    const float* __restrict__ b1_re, const float* __restrict__ b1_im,
    const float* __restrict__ b2_re, const float* __restrict__ b2_im) {
    __shared__ __align__(16) ushort xb[2][64][96];
    __shared__ __align__(16) ushort wb[2][96][104];

    const int mt = blockIdx.x;
    const int n  = blockIdx.y;
    const int b  = blockIdx.z;
    const int tid = threadIdx.x;
    const int lane = tid & 63;
    const int wv   = tid >> 6;
    const int m0 = mt * 64;
    float* base = io + ((size_t)b * 768 + (size_t)n * 96) * 4096;

    for (int idx = tid; idx < 96 * 64; idx += NTH) {
        int i = idx >> 6, mm = idx & 63;
        int m = m0 + mm;
        const float* row = base + (size_t)i * 4096;
        float re = 0.f, im = 0.f;
        if (m == 0) { re = row[0]; }
        else if (m == 2048) { re = row[1]; }
        else if (m < 2048) { float2 v = *(const float2*)(row + 2 * m); re = v.x; im = v.y; }
        xb[0][mm][i] = f2bf(re);
        xb[1][mm][i] = f2bf(im);
    }
    const float* W1r = w1_re + (size_t)n * 9216;
    const float* W1i = w1_im + (size_t)n * 9216;
    for (int idx = tid; idx < 9216; idx += NTH) {
        int i = idx / 96, o = idx - i * 96;
        wb[0][o][i] = f2bf(W1r[idx]);
        wb[1][o][i] = f2bf(W1i[idx]);
    }
    const int lane2 = tid & 63;
    const int lc = lane2 & 15;
    float b1r[6], b1i[6], b2r[6], b2i[6];
#pragma unroll
    for (int nt = 0; nt < 6; ++nt) {
        b1r[nt] = b1_re[n * 96 + nt * 16 + lc];
        b1i[nt] = b1_im[n * 96 + nt * 16 + lc];
        b2r[nt] = b2_re[n * 96 + nt * 16 + lc];
        b2i[nt] = b2_im[n * 96 + nt * 16 + lc];
    }
    __syncthreads();

    const int mw = wv * 16;
    const int kl = 8 * (lane & 48) >> 1;   // 8 * (lane>>4)
    const int klr = 8 * (lane >> 4);
    const int mrow = mw + lc;

    f32x4 accR[6], accI[6];
    const f32x4 zero = {0.f, 0.f, 0.f, 0.f};
#pragma unroll
    for (int nt = 0; nt < 6; ++nt) { accR[nt] = zero; accI[nt] = zero; }

#pragma unroll
    for (int kk = 0; kk < 3; ++kk) {
        int k0 = kk * 32 + klr;
        short8 ar = *(const short8*)&xb[0][mrow][k0];
        short8 ai = *(const short8*)&xb[1][mrow][k0];
        short8 nai;
#pragma unroll
        for (int j = 0; j < 8; ++j) nai[j] = ai[j] ^ (short)0x8000;
#pragma unroll
        for (int nt = 0; nt < 6; ++nt) {
            short8 br = *(const short8*)&wb[0][nt * 16 + lc][k0];
            short8 bi = *(const short8*)&wb[1][nt * 16 + lc][k0];
            accR[nt] = __builtin_amdgcn_mfma_f32_16x16x32_bf16(ar,  br, accR[nt], 0, 0, 0);
            accR[nt] = __builtin_amdgcn_mfma_f32_16x16x32_bf16(nai, bi, accR[nt], 0, 0, 0);
            accI[nt] = __builtin_amdgcn_mfma_f32_16x16x32_bf16(ar,  bi, accI[nt], 0, 0, 0);
            accI[nt] = __builtin_amdgcn_mfma_f32_16x16x32_bf16(ai,  br, accI[nt], 0, 0, 0);
        }
    }
#pragma unroll
    for (int nt = 0; nt < 6; ++nt) {
#pragma unroll
        for (int q = 0; q < 4; ++q) {
            int m = mw + 4 * (lane >> 4) + q;
            float hr = fmaxf(accR[nt][q] + b1r[nt], 0.f);
            float hi = fmaxf(accI[nt][q] + b1i[nt], 0.f);
            xb[0][m][nt * 16 + lc] = f2bf(hr);
            xb[1][m][nt * 16 + lc] = f2bf(hi);
        }
    }
    __syncthreads();

    const float* W2r = w2_re + (size_t)n * 9216;
    const float* W2i = w2_im + (size_t)n * 9216;
    for (int idx = tid; idx < 9216; idx += NTH) {
        int i = idx / 96, o = idx - i * 96;
        wb[0][o][i] = f2bf(W2r[idx]);
        wb[1][o][i] = f2bf(W2i[idx]);
    }
    __syncthreads();

#pragma unroll
    for (int nt = 0; nt < 6; ++nt) { accR[nt] = zero; accI[nt] = zero; }
#pragma unroll
    for (int kk = 0; kk < 3; ++kk) {
        int k0 = kk * 32 + klr;
        short8 ar = *(const short8*)&xb[0][mrow][k0];
        short8 ai = *(const short8*)&xb[1][mrow][k0];
        short8 nai;
#pragma unroll
        for (int j = 0; j < 8; ++j) nai[j] = ai[j] ^ (short)0x8000;
#pragma unroll
        for (int nt = 0; nt < 6; ++nt) {
            short8 br = *(const short8*)&wb[0][nt * 16 + lc][k0];
            short8 bi = *(const short8*)&wb[1][nt * 16 + lc][k0];
            accR[nt] = __builtin_amdgcn_mfma_f32_16x16x32_bf16(ar,  br, accR[nt], 0, 0, 0);
            accR[nt] = __builtin_amdgcn_mfma_f32_16x16x32_bf16(nai, bi, accR[nt], 0, 0, 0);
            accI[nt] = __builtin_amdgcn_mfma_f32_16x16x32_bf16(ar,  bi, accI[nt], 0, 0, 0);
            accI[nt] = __builtin_amdgcn_mfma_f32_16x16x32_bf16(ai,  br, accI[nt], 0, 0, 0);
        }
    }
#pragma unroll
    for (int nt = 0; nt < 6; ++nt) {
#pragma unroll
        for (int q = 0; q < 4; ++q) {
            int m = m0 + mw + 4 * (lane >> 4) + q;
            float vr = accR[nt][q] + b2r[nt];
            float vi = accI[nt][q] + b2i[nt];
            float sr = copysignf(fmaxf(fabsf(vr) - LAM, 0.f), vr);
            float si = copysignf(fmaxf(fabsf(vi) - LAM, 0.f), vi);
            float* row = base + (size_t)(nt * 16 + lc) * 4096;
            if (m == 0)          row[0] = sr;
            else if (m == 2048)  row[1] = sr;
            else if (m < 2048)   *(float2*)(row + 2 * m) = make_float2(sr, si);
        }
    }
}

// ---------------------------------------------------------------------------
// Inverse rfft per row (ortho) + residual add, in-place on packed spectrum.
// ---------------------------------------------------------------------------
__global__ __launch_bounds__(NTH) void k_irfft_add(const float* __restrict__ x,
                                                   float* __restrict__ io) {
    __shared__ float2 bufA[FFT_LDS_SZ];
    __shared__ float2 bufB[FFT_LDS_SZ];
    const int row = blockIdx.x;
    const float* xr = x + (size_t)row * 4096;
    float* orow = io + (size_t)row * 4096;
    const int tid = threadIdx.x;
    const float scale = 1.0f / 32.0f;

    for (int k = tid; k < 2048; k += NTH) {
        float Xr, Xi, Yr, Yi;
        if (k == 0) {
            Xr = orow[0]; Xi = 0.f; Yr = orow[1]; Yi = 0.f;
        } else {
            float2 a  = *(const float2*)(orow + 2 * k);
            float2 bq = *(const float2*)(orow + 2 * (2048 - k));
            Xr = a.x; Xi = a.y; Yr = bq.x; Yi = bq.y;
        }
        float Fer = 0.5f * (Xr + Yr), Fei = 0.5f * (Xi - Yi);
        float Dr  = 0.5f * (Xr - Yr), Di  = 0.5f * (Xi + Yi);
        float ang = (float)M_PI * (float)k / 2048.0f;
        float s, c;
        __sincosf(ang, &s, &c);
        float For = c * Dr - s * Di;
        float Foi = c * Di + s * Dr;
        bufA[pad(k)] = make_float2((Fer - Foi) * scale, (Fei + For) * scale);
    }
    __syncthreads();

    float2* Zt = fft2048_stockham(bufA, bufB, tid, 1.0f);

    for (int t = tid; t < 2048; t += NTH) {
        float2 z  = Zt[pad(t)];
        float2 xv = *(const float2*)(xr + 2 * t);
        *(float2*)(orow + 2 * t) = make_float2(z.x + xv.x, z.y + xv.y);
    }
}

// ---------------------------------------------------------------------------
extern "C" void kernel_launch(void* const* d_in, const int* in_sizes, int n_in,
                              void* d_out, int out_size, void* d_ws, size_t ws_size,
                              hipStream_t stream) {
    const float* x     = (const float*)d_in[0];
    const float* w1_re = (const float*)d_in[1];
    const float* w1_im = (const float*)d_in[2];
    const float* w2_re = (const float*)d_in[3];
    const float* w2_im = (const float*)d_in[4];
    const float* b1_re = (const float*)d_in[5];
    const float* b1_im = (const float*)d_in[6];
    const float* b2_re = (const float*)d_in[7];
    const float* b2_im = (const float*)d_in[8];
    float* out = (float*)d_out;

    k_rfft_fwd<<<12288, NTH, 0, stream>>>(x, out);
    if (ws_size >= (size_t)WS_WT_BYTES) {
        ushort* wt = (ushort*)d_ws;
        k_prep<<<(294912 + NTH - 1) / NTH, NTH, 0, stream>>>(w1_re, w1_im, w2_re, w2_im, wt);
        k_mix3<<<dim3(33, 8, 16), NTH, 0, stream>>>(out, wt, b1_re, b1_im, b2_re, b2_im);
    } else {
        k_mix_fallback<<<dim3(33, 8, 16), NTH, 0, stream>>>(out, w1_re, w1_im, w2_re, w2_im,
                                                            b1_re, b1_im, b2_re, b2_im);
    }
    k_irfft_add<<<12288, NTH, 0, stream>>>(x, out);
}